// Round 1
// baseline (1083.923 us; speedup 1.0000x reference)
//
#include <hip/hip_runtime.h>
#include <hip/hip_bf16.h>
#include <math.h>

// ---------------------------------------------------------------------------
// DotScaledAttention: q=(x0@Wq+bq)/sqrt(512); k=x1@Wk+bk; v=x2@Wk+bk;
// out = causal_softmax(q k^T) v.   B=8 N=2048 d_emb=1024 d_red=512, fp32 io.
// Strategy: bf16 MFMA (16x16x32) for all GEMMs, fp32 accumulate + fp32 softmax.
// ---------------------------------------------------------------------------

typedef __bf16 bf16_t;
typedef __attribute__((ext_vector_type(8))) __bf16 bf16x8;
typedef __attribute__((ext_vector_type(4))) __bf16 bf16x4;
typedef __attribute__((ext_vector_type(4))) float f32x4;

#define MFMA16(a, b, c) __builtin_amdgcn_mfma_f32_16x16x32_bf16((a), (b), (c), 0, 0, 0)

#define XSTR 72  // LDS row stride (bf16 elems): 144B = 9*16B, keeps 16B align, breaks pow2 banks

// --------------------------- W transpose + convert --------------------------
// W [1024][512] f32  ->  Wt [512][1024] bf16
__global__ __launch_bounds__(256) void wt_kernel(const float* __restrict__ Wq,
                                                 const float* __restrict__ Wk,
                                                 bf16_t* __restrict__ Wtq,
                                                 bf16_t* __restrict__ Wtk) {
  __shared__ float tile[32][33];
  int bid = blockIdx.x;
  int mat = bid >> 9;  // 512 tiles per matrix
  int rem = bid & 511;
  int kt = rem >> 4, nt = rem & 15;
  int k0 = kt * 32, n0 = nt * 32;
  const float* src = mat ? Wk : Wq;
  bf16_t* dst = mat ? Wtk : Wtq;
  int t = threadIdx.x;
  int r = t >> 3, c4 = (t & 7) * 4;
  float4 v = *(const float4*)(src + (k0 + r) * 512 + n0 + c4);
  tile[r][c4 + 0] = v.x; tile[r][c4 + 1] = v.y;
  tile[r][c4 + 2] = v.z; tile[r][c4 + 3] = v.w;
  __syncthreads();
  bf16x4 o;
  o[0] = (bf16_t)tile[c4 + 0][r];
  o[1] = (bf16_t)tile[c4 + 1][r];
  o[2] = (bf16_t)tile[c4 + 2][r];
  o[3] = (bf16_t)tile[c4 + 3][r];
  *(bf16x4*)(dst + (n0 + r) * 1024 + k0 + c4) = o;
}

// ------------------------------- projections --------------------------------
// grid 3072: mat(3) x mblk(128) x nblk(8).  Tile BM=128 BN=64 BK=64.
// 4 waves: wave w owns rows [w*32, w*32+32), all 64 cols -> acc[2][4] 16x16 frags.
__global__ __launch_bounds__(256) void proj_kernel(
    const float* __restrict__ x0, const float* __restrict__ x1, const float* __restrict__ x2,
    const bf16_t* __restrict__ Wtq, const bf16_t* __restrict__ Wtk,
    const float* __restrict__ bq, const float* __restrict__ bk,
    bf16_t* __restrict__ qo, bf16_t* __restrict__ ko, bf16_t* __restrict__ vT) {
  __shared__ __align__(16) bf16_t Xs[128 * XSTR];
  __shared__ __align__(16) bf16_t Ws[64 * XSTR];
  int bid = blockIdx.x;
  int mat = bid >> 10;
  int rem = bid & 1023;
  int mblk = rem >> 3, nblk = rem & 7;  // consecutive bids share the X tile (L2)
  const float* xsrc = (mat == 0) ? x0 : ((mat == 1) ? x1 : x2);
  const bf16_t* wsrc = (mat == 0) ? Wtq : Wtk;
  int tid = threadIdx.x;
  int wave = tid >> 6, lane = tid & 63, lhi = lane >> 4, llo = lane & 15;

  f32x4 acc[2][4];
#pragma unroll
  for (int i = 0; i < 2; ++i)
#pragma unroll
    for (int j = 0; j < 4; ++j) acc[i][j] = (f32x4){0.f, 0.f, 0.f, 0.f};

  int xrow = tid >> 1, xseg = tid & 1;  // X stage: 2 thr/row, 32 f32 each
  int wrow = tid >> 2, wseg = tid & 3;  // W stage: 4 thr/row, 16 bf16 each
  const float* xbase = xsrc + (size_t)(mblk * 128 + xrow) * 1024 + xseg * 32;
  const bf16_t* wbase = wsrc + (size_t)(nblk * 64 + wrow) * 1024 + wseg * 16;

  for (int kt = 0; kt < 16; ++kt) {
    int k0 = kt * 64;
    bf16_t tmp[32];
#pragma unroll
    for (int i = 0; i < 8; ++i) {
      float4 v = *(const float4*)(xbase + k0 + i * 4);
      tmp[i * 4 + 0] = (bf16_t)v.x; tmp[i * 4 + 1] = (bf16_t)v.y;
      tmp[i * 4 + 2] = (bf16_t)v.z; tmp[i * 4 + 3] = (bf16_t)v.w;
    }
#pragma unroll
    for (int i = 0; i < 4; ++i)
      *(bf16x8*)(&Xs[xrow * XSTR + xseg * 32 + i * 8]) = *(bf16x8*)(&tmp[i * 8]);
#pragma unroll
    for (int i = 0; i < 2; ++i)
      *(bf16x8*)(&Ws[wrow * XSTR + wseg * 16 + i * 8]) = *(const bf16x8*)(wbase + k0 + i * 8);
    __syncthreads();
#pragma unroll
    for (int ks = 0; ks < 2; ++ks) {
      bf16x8 af[2], bfr[4];
#pragma unroll
      for (int mt = 0; mt < 2; ++mt)
        af[mt] = *(const bf16x8*)(&Xs[(wave * 32 + mt * 16 + llo) * XSTR + ks * 32 + lhi * 8]);
#pragma unroll
      for (int nt = 0; nt < 4; ++nt)
        bfr[nt] = *(const bf16x8*)(&Ws[(nt * 16 + llo) * XSTR + ks * 32 + lhi * 8]);
#pragma unroll
      for (int mt = 0; mt < 2; ++mt)
#pragma unroll
        for (int nt = 0; nt < 4; ++nt)
          acc[mt][nt] = MFMA16(af[mt], bfr[nt], acc[mt][nt]);
    }
    __syncthreads();
  }

  const float* bias = (mat == 0) ? bq : bk;
  float scale = (mat == 0) ? 0.044194173824159216f : 1.0f;  // 1/sqrt(512)
#pragma unroll
  for (int mt = 0; mt < 2; ++mt) {
#pragma unroll
    for (int nt = 0; nt < 4; ++nt) {
      int n = nblk * 64 + nt * 16 + llo;
      float bv = bias[n];
      int rowb = mblk * 128 + wave * 32 + mt * 16 + lhi * 4;
      float vals[4];
#pragma unroll
      for (int r = 0; r < 4; ++r) vals[r] = (acc[mt][nt][r] + bv) * scale;
      if (mat == 0) {
#pragma unroll
        for (int r = 0; r < 4; ++r) qo[(size_t)(rowb + r) * 512 + n] = (bf16_t)vals[r];
      } else if (mat == 1) {
#pragma unroll
        for (int r = 0; r < 4; ++r) ko[(size_t)(rowb + r) * 512 + n] = (bf16_t)vals[r];
      } else {
        int batch = rowb >> 11, tok = rowb & 2047;  // v stored transposed: vT[b*512+d][token]
        bf16x4 o;
        o[0] = (bf16_t)vals[0]; o[1] = (bf16_t)vals[1];
        o[2] = (bf16_t)vals[2]; o[3] = (bf16_t)vals[3];
        *(bf16x4*)(vT + (size_t)(batch * 512 + n) * 2048 + tok) = o;
      }
    }
  }
}

// ------------------------------- attention ----------------------------------
// One wave = 16 q-rows, full D=512 in registers. K/V fragments straight from
// global (L1/L2). mode 0: static balanced tiles, direct out. mode 1: 2048
// half-tile jobs via atomic queue (heavy first), partials + merge.
__global__ __launch_bounds__(256, 1) void attn_kernel(
    const bf16_t* __restrict__ qg, const bf16_t* __restrict__ kg,
    const bf16_t* __restrict__ vTg, float* __restrict__ out,
    float* __restrict__ Opart, float* __restrict__ msum, float* __restrict__ lsum,
    int* __restrict__ ctr, int mode) {
  __shared__ __align__(16) bf16_t Plds[4][16 * XSTR];
  int tid = threadIdx.x;
  int wave = tid >> 6, lane = tid & 63, lhi = lane >> 4, llo = lane & 15;
  bf16_t* Pb = &Plds[wave][0];

  for (int iter = 0;; ++iter) {
    int batch, tile, klo, khi, job = 0;
    if (mode == 0) {
      if (iter) break;
      int j = blockIdx.x & 31;
      batch = blockIdx.x >> 5;
      tile = (wave == 0) ? j : (wave == 1) ? 63 - j : (wave == 2) ? 64 + j : 127 - j;
      klo = 0;
      khi = (tile + 1) * 16;
    } else {
      if (lane == 0) job = atomicAdd(ctr, 1);
      job = __shfl(job, 0, 64);
      if (job >= 2048) break;
      int tp = job >> 4;
      tile = 127 - tp;           // heavy tiles first
      batch = (job >> 1) & 7;
      int half = job & 1;
      int kend = (tile + 1) * 16;
      int mid = ((kend >> 1) + 63) & ~63;  // split on 64-key boundary
      if (mid > kend) mid = kend;
      klo = half ? mid : 0;
      khi = half ? kend : mid;
    }
    int q0 = tile * 16;

    // preload Q fragments (A-layout: m=llo, k=lhi*8+j), all 16 K-steps
    const bf16_t* qrowp = qg + (size_t)((batch << 11) + q0 + llo) * 512;
    bf16x8 qf[16];
#pragma unroll
    for (int kk = 0; kk < 16; ++kk)
      qf[kk] = *(const bf16x8*)(qrowp + kk * 32 + lhi * 8);

    f32x4 Of[32];
#pragma unroll
    for (int i = 0; i < 32; ++i) Of[i] = (f32x4){0.f, 0.f, 0.f, 0.f};
    float m_i[4] = {-INFINITY, -INFINITY, -INFINITY, -INFINITY};
    float l_i[4] = {0.f, 0.f, 0.f, 0.f};

    const bf16_t* kbase = kg + ((size_t)batch << 11) * 512;
    const bf16_t* vbase = vTg + ((size_t)batch << 9) * 2048;

    for (int key0 = klo; key0 < khi; key0 += 64) {
      int nact = (khi - key0) >> 4;
      if (nact > 4) nact = 4;
      f32x4 sf[4];
#pragma unroll
      for (int nt = 0; nt < 4; ++nt) sf[nt] = (f32x4){0.f, 0.f, 0.f, 0.f};
#pragma unroll
      for (int kk = 0; kk < 16; ++kk) {
#pragma unroll
        for (int nt = 0; nt < 4; ++nt) {
          if (nt < nact) {
            bf16x8 kf = *(const bf16x8*)(kbase + (size_t)(key0 + nt * 16 + llo) * 512 + kk * 32 + lhi * 8);
            sf[nt] = MFMA16(qf[kk], kf, sf[nt]);
          }
        }
      }
      // causal mask (C layout: col=llo within n-tile, row=lhi*4+r) + row max
      float vm[4];
#pragma unroll
      for (int r = 0; r < 4; ++r) vm[r] = -INFINITY;
#pragma unroll
      for (int nt = 0; nt < 4; ++nt) {
        if (nt < nact) {
          int key = key0 + nt * 16 + llo;
#pragma unroll
          for (int r = 0; r < 4; ++r) {
            int qrow = q0 + lhi * 4 + r;
            if (key > qrow) sf[nt][r] = -INFINITY;
            vm[r] = fmaxf(vm[r], sf[nt][r]);
          }
        }
      }
#pragma unroll
      for (int r = 0; r < 4; ++r) {
        vm[r] = fmaxf(vm[r], __shfl_xor(vm[r], 1, 64));
        vm[r] = fmaxf(vm[r], __shfl_xor(vm[r], 2, 64));
        vm[r] = fmaxf(vm[r], __shfl_xor(vm[r], 4, 64));
        vm[r] = fmaxf(vm[r], __shfl_xor(vm[r], 8, 64));
      }
      float alpha[4];
      int resc = 0;
#pragma unroll
      for (int r = 0; r < 4; ++r) {
        float mn = fmaxf(m_i[r], vm[r]);
        alpha[r] = __expf(m_i[r] - mn);  // exp(-inf - finite) = 0, never NaN here
        m_i[r] = mn;
        resc |= (alpha[r] < 1.0f) ? 1 : 0;
      }
      // P = exp(s-m) -> LDS (bf16), distributed l update
#pragma unroll
      for (int r = 0; r < 4; ++r) {
        float ps = 0.f;
#pragma unroll
        for (int nt = 0; nt < 4; ++nt) {
          float p = (nt < nact) ? __expf(sf[nt][r] - m_i[r]) : 0.f;
          ps += p;
          Pb[(lhi * 4 + r) * XSTR + nt * 16 + llo] = (bf16_t)p;
        }
        l_i[r] = alpha[r] * l_i[r] + ps;
      }
      if (__any(resc)) {
#pragma unroll
        for (int i = 0; i < 32; ++i) {
#pragma unroll
          for (int r = 0; r < 4; ++r) Of[i][r] *= alpha[r];
        }
      }
      // PV: A = P from LDS (layout transform), B = vT fragments from global
#pragma unroll
      for (int ks = 0; ks < 2; ++ks) {
        bf16x8 pa = *(const bf16x8*)(&Pb[llo * XSTR + ks * 32 + lhi * 8]);
#pragma unroll
        for (int nt = 0; nt < 32; ++nt) {
          bf16x8 bv = *(const bf16x8*)(vbase + (size_t)(nt * 16 + llo) * 2048 + key0 + ks * 32 + lhi * 8);
          Of[nt] = MFMA16(pa, bv, Of[nt]);
        }
      }
    }  // key loop

    // l reduction across the 16 col-lanes
#pragma unroll
    for (int r = 0; r < 4; ++r) {
      l_i[r] += __shfl_xor(l_i[r], 1, 64);
      l_i[r] += __shfl_xor(l_i[r], 2, 64);
      l_i[r] += __shfl_xor(l_i[r], 4, 64);
      l_i[r] += __shfl_xor(l_i[r], 8, 64);
    }
    if (mode == 0) {
      float linv[4];
#pragma unroll
      for (int r = 0; r < 4; ++r) linv[r] = 1.0f / l_i[r];
      float* ob = out + ((size_t)((batch << 11) + q0)) * 512;
#pragma unroll
      for (int nt = 0; nt < 32; ++nt)
#pragma unroll
        for (int r = 0; r < 4; ++r)
          ob[(size_t)(lhi * 4 + r) * 512 + nt * 16 + llo] = Of[nt][r] * linv[r];
    } else {
      if (khi > klo) {
        float* op = Opart + (size_t)job * (16 * 512);
#pragma unroll
        for (int nt = 0; nt < 32; ++nt)
#pragma unroll
          for (int r = 0; r < 4; ++r)
            op[(size_t)(lhi * 4 + r) * 512 + nt * 16 + llo] = Of[nt][r];
      }
      if (llo == 0) {
#pragma unroll
        for (int r = 0; r < 4; ++r) {
          msum[job * 16 + lhi * 4 + r] = m_i[r];
          lsum[job * 16 + lhi * 4 + r] = l_i[r];
        }
      }
    }
  }
}

// ------------------------------- merge (mode 1) -----------------------------
__global__ __launch_bounds__(256) void merge_kernel(const float* __restrict__ Opart,
                                                    const float* __restrict__ msum,
                                                    const float* __restrict__ lsum,
                                                    float* __restrict__ out) {
  int idx = blockIdx.x * 256 + threadIdx.x;
  int d = idx & 511;
  int qg = idx >> 9;
  int batch = qg >> 11, qr = qg & 2047;
  int tile = qr >> 4, row = qr & 15;
  int tp = 127 - tile;
  int j0 = (tp << 4) | (batch << 1);
  int j1 = j0 | 1;
  float m0 = msum[j0 * 16 + row], m1 = msum[j1 * 16 + row];
  float l0 = lsum[j0 * 16 + row], l1 = lsum[j1 * 16 + row];
  float M = fmaxf(m0, m1);
  float a0 = __expf(m0 - M), a1 = __expf(m1 - M);
  float denom = a0 * l0 + a1 * l1;
  float o0 = Opart[(size_t)j0 * (16 * 512) + row * 512 + d];
  float o1 = (l1 > 0.f) ? Opart[(size_t)j1 * (16 * 512) + row * 512 + d] : 0.f;
  out[idx] = (a0 * o0 + a1 * o1) / denom;
}

// ------------------------------- launcher -----------------------------------
extern "C" void kernel_launch(void* const* d_in, const int* in_sizes, int n_in,
                              void* d_out, int out_size, void* d_ws, size_t ws_size,
                              hipStream_t stream) {
  (void)in_sizes; (void)n_in; (void)out_size;
  const float* x0 = (const float*)d_in[0];
  const float* x1 = (const float*)d_in[1];
  const float* x2 = (const float*)d_in[2];
  const float* Wq = (const float*)d_in[3];
  const float* bq = (const float*)d_in[4];
  const float* Wk = (const float*)d_in[5];
  const float* bk = (const float*)d_in[6];
  float* out = (float*)d_out;
  char* ws = (char*)d_ws;
  const size_t MB = 1ull << 20;
  bf16_t* Wtq = (bf16_t*)(ws + 0 * MB);            // 1 MB
  bf16_t* Wtk = (bf16_t*)(ws + 1 * MB);            // 1 MB
  bf16_t* qw  = (bf16_t*)(ws + 2 * MB);            // 16 MB
  bf16_t* kw  = (bf16_t*)(ws + 18 * MB);           // 16 MB
  bf16_t* vT  = (bf16_t*)(ws + 34 * MB);           // 16 MB
  float* msum = (float*)(ws + 50 * MB);            // 128 KB
  float* lsum = (float*)(ws + 50 * MB + (1 << 17));// 128 KB
  int* ctr    = (int*)(ws + 50 * MB + (1 << 18));  // 4 B
  float* Opart = (float*)(ws + 51 * MB);           // 64 MB (split mode only)
  int split = (ws_size >= (size_t)(115 * MB)) ? 1 : 0;

  hipLaunchKernelGGL(wt_kernel, dim3(1024), dim3(256), 0, stream, Wq, Wk, Wtq, Wtk);
  hipLaunchKernelGGL(proj_kernel, dim3(3072), dim3(256), 0, stream,
                     x0, x1, x2, Wtq, Wtk, bq, bk, qw, kw, vT);
  if (split) {
    hipMemsetAsync(ctr, 0, 4, stream);
    hipLaunchKernelGGL(attn_kernel, dim3(256), dim3(256), 0, stream,
                       qw, kw, vT, out, Opart, msum, lsum, ctr, 1);
    hipLaunchKernelGGL(merge_kernel, dim3(32768), dim3(256), 0, stream,
                       Opart, msum, lsum, out);
  } else {
    hipLaunchKernelGGL(attn_kernel, dim3(256), dim3(256), 0, stream,
                       qw, kw, vT, out, Opart, msum, lsum, ctr, 0);
  }
}

// Round 2
// 689.976 us; speedup vs baseline: 1.5710x; 1.5710x over previous
//
#include <hip/hip_runtime.h>
#include <hip/hip_bf16.h>
#include <math.h>

// ---------------------------------------------------------------------------
// DotScaledAttention: q=(x0@Wq+bq)/sqrt(512); k=x1@Wk+bk; v=x2@Wk+bk;
// out = causal_softmax(q k^T) v.   B=8 N=2048 d_emb=1024 d_red=512, fp32 io.
// R2: block-cooperative flash tile (64 q-rows), K/V staged in LDS via
// global_load_lds (16B, XOR-swizzled), 480 balanced jobs + merge.
// ---------------------------------------------------------------------------

typedef __bf16 bf16_t;
typedef __attribute__((ext_vector_type(8))) __bf16 bf16x8;
typedef __attribute__((ext_vector_type(4))) __bf16 bf16x4;
typedef __attribute__((ext_vector_type(4))) float f32x4;

#define MFMA16(a, b, c) __builtin_amdgcn_mfma_f32_16x16x32_bf16((a), (b), (c), 0, 0, 0)

#define XSTR 72  // P-buffer row stride (bf16 elems)

__device__ __forceinline__ void stage16(const void* g, void* l) {
  // async global->LDS DMA, 16B per lane; LDS dest = wave-uniform base + lane*16
  __builtin_amdgcn_global_load_lds(
      (__attribute__((address_space(1))) void*)(uintptr_t)g,
      (__attribute__((address_space(3))) void*)l, 16, 0, 0);
}

// --------------------------- W transpose + convert --------------------------
__global__ __launch_bounds__(256) void wt_kernel(const float* __restrict__ Wq,
                                                 const float* __restrict__ Wk,
                                                 bf16_t* __restrict__ Wtq,
                                                 bf16_t* __restrict__ Wtk) {
  __shared__ float tile[32][33];
  int bid = blockIdx.x;
  int mat = bid >> 9;
  int rem = bid & 511;
  int kt = rem >> 4, nt = rem & 15;
  int k0 = kt * 32, n0 = nt * 32;
  const float* src = mat ? Wk : Wq;
  bf16_t* dst = mat ? Wtk : Wtq;
  int t = threadIdx.x;
  int r = t >> 3, c4 = (t & 7) * 4;
  float4 v = *(const float4*)(src + (k0 + r) * 512 + n0 + c4);
  tile[r][c4 + 0] = v.x; tile[r][c4 + 1] = v.y;
  tile[r][c4 + 2] = v.z; tile[r][c4 + 3] = v.w;
  __syncthreads();
  bf16x4 o;
  o[0] = (bf16_t)tile[c4 + 0][r];
  o[1] = (bf16_t)tile[c4 + 1][r];
  o[2] = (bf16_t)tile[c4 + 2][r];
  o[3] = (bf16_t)tile[c4 + 3][r];
  *(bf16x4*)(dst + (n0 + r) * 1024 + k0 + c4) = o;
}

// ------------------------------- projections --------------------------------
__global__ __launch_bounds__(256) void proj_kernel(
    const float* __restrict__ x0, const float* __restrict__ x1, const float* __restrict__ x2,
    const bf16_t* __restrict__ Wtq, const bf16_t* __restrict__ Wtk,
    const float* __restrict__ bq, const float* __restrict__ bk,
    bf16_t* __restrict__ qo, bf16_t* __restrict__ ko, bf16_t* __restrict__ vT) {
  __shared__ __align__(16) bf16_t Xs[128 * XSTR];
  __shared__ __align__(16) bf16_t Ws[64 * XSTR];
  int bid = blockIdx.x;
  int mat = bid >> 10;
  int rem = bid & 1023;
  int mblk = rem >> 3, nblk = rem & 7;
  const float* xsrc = (mat == 0) ? x0 : ((mat == 1) ? x1 : x2);
  const bf16_t* wsrc = (mat == 0) ? Wtq : Wtk;
  int tid = threadIdx.x;
  int wave = tid >> 6, lane = tid & 63, lhi = lane >> 4, llo = lane & 15;

  f32x4 acc[2][4];
#pragma unroll
  for (int i = 0; i < 2; ++i)
#pragma unroll
    for (int j = 0; j < 4; ++j) acc[i][j] = (f32x4){0.f, 0.f, 0.f, 0.f};

  int xrow = tid >> 1, xseg = tid & 1;
  int wrow = tid >> 2, wseg = tid & 3;
  const float* xbase = xsrc + (size_t)(mblk * 128 + xrow) * 1024 + xseg * 32;
  const bf16_t* wbase = wsrc + (size_t)(nblk * 64 + wrow) * 1024 + wseg * 16;

  for (int kt = 0; kt < 16; ++kt) {
    int k0 = kt * 64;
    bf16_t tmp[32];
#pragma unroll
    for (int i = 0; i < 8; ++i) {
      float4 v = *(const float4*)(xbase + k0 + i * 4);
      tmp[i * 4 + 0] = (bf16_t)v.x; tmp[i * 4 + 1] = (bf16_t)v.y;
      tmp[i * 4 + 2] = (bf16_t)v.z; tmp[i * 4 + 3] = (bf16_t)v.w;
    }
#pragma unroll
    for (int i = 0; i < 4; ++i)
      *(bf16x8*)(&Xs[xrow * XSTR + xseg * 32 + i * 8]) = *(bf16x8*)(&tmp[i * 8]);
#pragma unroll
    for (int i = 0; i < 2; ++i)
      *(bf16x8*)(&Ws[wrow * XSTR + wseg * 16 + i * 8]) = *(const bf16x8*)(wbase + k0 + i * 8);
    __syncthreads();
#pragma unroll
    for (int ks = 0; ks < 2; ++ks) {
      bf16x8 af[2], bfr[4];
#pragma unroll
      for (int mt = 0; mt < 2; ++mt)
        af[mt] = *(const bf16x8*)(&Xs[(wave * 32 + mt * 16 + llo) * XSTR + ks * 32 + lhi * 8]);
#pragma unroll
      for (int nt = 0; nt < 4; ++nt)
        bfr[nt] = *(const bf16x8*)(&Ws[(nt * 16 + llo) * XSTR + ks * 32 + lhi * 8]);
#pragma unroll
      for (int mt = 0; mt < 2; ++mt)
#pragma unroll
        for (int nt = 0; nt < 4; ++nt)
          acc[mt][nt] = MFMA16(af[mt], bfr[nt], acc[mt][nt]);
    }
    __syncthreads();
  }

  const float* bias = (mat == 0) ? bq : bk;
  float scale = (mat == 0) ? 0.044194173824159216f : 1.0f;  // 1/sqrt(512)
#pragma unroll
  for (int mt = 0; mt < 2; ++mt) {
#pragma unroll
    for (int nt = 0; nt < 4; ++nt) {
      int n = nblk * 64 + nt * 16 + llo;
      float bv = bias[n];
      int rowb = mblk * 128 + wave * 32 + mt * 16 + lhi * 4;
      float vals[4];
#pragma unroll
      for (int r = 0; r < 4; ++r) vals[r] = (acc[mt][nt][r] + bv) * scale;
      if (mat == 0) {
#pragma unroll
        for (int r = 0; r < 4; ++r) qo[(size_t)(rowb + r) * 512 + n] = (bf16_t)vals[r];
      } else if (mat == 1) {
#pragma unroll
        for (int r = 0; r < 4; ++r) ko[(size_t)(rowb + r) * 512 + n] = (bf16_t)vals[r];
      } else {
        int batch = rowb >> 11, tok = rowb & 2047;
        bf16x4 o;
        o[0] = (bf16_t)vals[0]; o[1] = (bf16_t)vals[1];
        o[2] = (bf16_t)vals[2]; o[3] = (bf16_t)vals[3];
        *(bf16x4*)(vT + (size_t)(batch * 512 + n) * 2048 + tok) = o;
      }
    }
  }
}

// ------------------------------- attention ----------------------------------
// Block = 64 q-rows (4 waves x 16 rows), one (batch,tile,chunk) job.
// K-block of 64 keys staged into LDS in two 256-d chunks; V (as vT) likewise.
// Jobs per batch: tiles 0..11 -> 1 chunk, 12..23 -> 2, 24..31 -> 3 (<=768 keys).
__global__ __launch_bounds__(256, 2) void attn_kernel(
    const bf16_t* __restrict__ qg, const bf16_t* __restrict__ kg,
    const bf16_t* __restrict__ vTg, float* __restrict__ out,
    float* __restrict__ Opart, float* __restrict__ msum, float* __restrict__ lsum) {
  __shared__ __align__(16) bf16_t Kb[64 * 256];   // 32KB [key][32 swizzled 16B segs]
  __shared__ __align__(16) bf16_t Vb[256 * 64];   // 32KB [d_local][8 swizzled 16B segs]
  __shared__ __align__(16) bf16_t Plds[4][16 * XSTR];  // 9.2KB per-wave P

  int job = blockIdx.x;  // 0..479
  int b = job / 60, jj = job - b * 60;
  int t, c, n;
  if (jj < 12)      { t = jj;                 c = 0;             n = 1; }
  else if (jj < 36) { t = 12 + (jj - 12) / 2; c = (jj - 12) & 1; n = 2; }
  else              { t = 24 + (jj - 36) / 3; c = (jj - 36) % 3; n = 3; }
  int kbs = t + 1;                    // key-blocks in full causal range
  int csz = (kbs + n - 1) / n;
  int kb_lo = c * csz;
  int kb_hi = min(kbs, kb_lo + csz);
  int q0 = t * 64;

  int tid = threadIdx.x;
  int wave = tid >> 6, lane = tid & 63, lhi = lane >> 4, llo = lane & 15;
  bf16_t* Pb = &Plds[wave][0];

  const bf16_t* kbase = kg + ((size_t)b << 11) * 512;
  const bf16_t* vbase = vTg + ((size_t)b << 9) * 2048;

  // Q fragments (A-layout: m=llo, k=lhi*8+j), rows q0+wave*16+llo, all 512 d
  const bf16_t* qrowp = qg + (size_t)((b << 11) + q0 + wave * 16 + llo) * 512;
  bf16x8 qf[16];
#pragma unroll
  for (int kk = 0; kk < 16; ++kk)
    qf[kk] = *(const bf16x8*)(qrowp + kk * 32 + lhi * 8);

  f32x4 Of[32];
#pragma unroll
  for (int i = 0; i < 32; ++i) Of[i] = (f32x4){0.f, 0.f, 0.f, 0.f};
  float m_i[4] = {-INFINITY, -INFINITY, -INFINITY, -INFINITY};
  float l_i[4] = {0.f, 0.f, 0.f, 0.f};

  // prologue: stage K chunk 0 of first key-block
  {
    int key0 = kb_lo * 64;
#pragma unroll
    for (int i = 0; i < 8; ++i) {
      int dseg = wave * 512 + i * 64 + lane;
      int key = dseg >> 5, phys = dseg & 31;
      int lseg = phys ^ (key & 7);
      stage16(kbase + (size_t)(key0 + key) * 512 + lseg * 8,
              &Kb[(wave * 512 + i * 64) * 8]);
    }
  }

  for (int kb = kb_lo; kb < kb_hi; ++kb) {
    int key0 = kb * 64;
    f32x4 sf[4];
#pragma unroll
    for (int nt = 0; nt < 4; ++nt) sf[nt] = (f32x4){0.f, 0.f, 0.f, 0.f};

#pragma unroll
    for (int half = 0; half < 2; ++half) {
      __syncthreads();  // K chunk `half` staged; LDS consumers of prev phase done
      // compute on chunk `half`: kk in [half*8, half*8+8)
#pragma unroll
      for (int kkl = 0; kkl < 8; ++kkl) {
#pragma unroll
        for (int nt = 0; nt < 4; ++nt) {
          int key = nt * 16 + llo;
          int phys = (kkl * 4 + lhi) ^ (llo & 7);
          bf16x8 kf = *(const bf16x8*)(&Kb[key * 256 + phys * 8]);
          sf[nt] = MFMA16(qf[half * 8 + kkl], kf, sf[nt]);
        }
      }
      __syncthreads();  // Kb free
      if (half == 0) {
        // stage K chunk 1
#pragma unroll
        for (int i = 0; i < 8; ++i) {
          int dseg = wave * 512 + i * 64 + lane;
          int key = dseg >> 5, phys = dseg & 31;
          int lseg = phys ^ (key & 7);
          stage16(kbase + (size_t)(key0 + key) * 512 + 256 + lseg * 8,
                  &Kb[(wave * 512 + i * 64) * 8]);
        }
      } else {
        // stage V chunk 0 (d 0..255); softmax below overlaps this DMA
#pragma unroll
        for (int i = 0; i < 8; ++i) {
          int f = wave * 512 + i * 64 + lane;
          int dl = f >> 3, phys = f & 7;
          int lseg = phys ^ (dl & 7);
          stage16(vbase + (size_t)dl * 2048 + key0 + lseg * 8,
                  &Vb[(wave * 512 + i * 64) * 8]);
        }
      }
    }

    // ---- softmax (per-wave, overlaps V chunk-0 DMA) ----
    if (kb == t) {  // diagonal block: causal mask
#pragma unroll
      for (int nt = 0; nt < 4; ++nt) {
        int kloc = nt * 16 + llo;
#pragma unroll
        for (int r = 0; r < 4; ++r)
          if (kloc > wave * 16 + lhi * 4 + r) sf[nt][r] = -INFINITY;
      }
    }
    float vm[4];
#pragma unroll
    for (int r = 0; r < 4; ++r) {
      vm[r] = fmaxf(fmaxf(sf[0][r], sf[1][r]), fmaxf(sf[2][r], sf[3][r]));
      vm[r] = fmaxf(vm[r], __shfl_xor(vm[r], 1, 64));
      vm[r] = fmaxf(vm[r], __shfl_xor(vm[r], 2, 64));
      vm[r] = fmaxf(vm[r], __shfl_xor(vm[r], 4, 64));
      vm[r] = fmaxf(vm[r], __shfl_xor(vm[r], 8, 64));
    }
    float alpha[4];
    int resc = 0;
#pragma unroll
    for (int r = 0; r < 4; ++r) {
      float mn = fmaxf(m_i[r], vm[r]);
      alpha[r] = __expf(m_i[r] - mn);
      m_i[r] = mn;
      resc |= (alpha[r] < 1.0f) ? 1 : 0;
    }
#pragma unroll
    for (int r = 0; r < 4; ++r) {
      float ps = 0.f;
#pragma unroll
      for (int nt = 0; nt < 4; ++nt) {
        float p = __expf(sf[nt][r] - m_i[r]);
        ps += p;
        Pb[(lhi * 4 + r) * XSTR + nt * 16 + llo] = (bf16_t)p;
      }
      l_i[r] = alpha[r] * l_i[r] + ps;
    }
    if (__any(resc)) {
#pragma unroll
      for (int i = 0; i < 32; ++i)
#pragma unroll
        for (int r = 0; r < 4; ++r) Of[i][r] *= alpha[r];
    }

    // ---- PV in two 256-d chunks ----
#pragma unroll
    for (int vc = 0; vc < 2; ++vc) {
      __syncthreads();  // V chunk vc staged
#pragma unroll
      for (int ks = 0; ks < 2; ++ks) {
        bf16x8 pa = *(const bf16x8*)(&Pb[llo * XSTR + ks * 32 + lhi * 8]);
#pragma unroll
        for (int ntl = 0; ntl < 16; ++ntl) {
          int dl = ntl * 16 + llo;
          int phys = (ks * 4 + lhi) ^ (llo & 7);
          bf16x8 bv = *(const bf16x8*)(&Vb[dl * 64 + phys * 8]);
          Of[vc * 16 + ntl] = MFMA16(pa, bv, Of[vc * 16 + ntl]);
        }
      }
      __syncthreads();  // Vb free
      if (vc == 0) {
        // stage V chunk 1 (d 256..511)
#pragma unroll
        for (int i = 0; i < 8; ++i) {
          int f = wave * 512 + i * 64 + lane;
          int dl = f >> 3, phys = f & 7;
          int lseg = phys ^ (dl & 7);
          stage16(vbase + (size_t)(256 + dl) * 2048 + key0 + lseg * 8,
                  &Vb[(wave * 512 + i * 64) * 8]);
        }
      } else if (kb + 1 < kb_hi) {
        // stage K chunk 0 of next key-block
#pragma unroll
        for (int i = 0; i < 8; ++i) {
          int dseg = wave * 512 + i * 64 + lane;
          int key = dseg >> 5, phys = dseg & 31;
          int lseg = phys ^ (key & 7);
          stage16(kbase + (size_t)(key0 + 64 + key) * 512 + lseg * 8,
                  &Kb[(wave * 512 + i * 64) * 8]);
        }
      }
    }
  }  // kb loop

  // l reduction across the 16 col-lanes
#pragma unroll
  for (int r = 0; r < 4; ++r) {
    l_i[r] += __shfl_xor(l_i[r], 1, 64);
    l_i[r] += __shfl_xor(l_i[r], 2, 64);
    l_i[r] += __shfl_xor(l_i[r], 4, 64);
    l_i[r] += __shfl_xor(l_i[r], 8, 64);
  }

  if (n == 1) {
    float linv[4];
#pragma unroll
    for (int r = 0; r < 4; ++r) linv[r] = 1.0f / l_i[r];
    float* ob = out + (size_t)((b << 11) + q0 + wave * 16) * 512;
#pragma unroll
    for (int nt = 0; nt < 32; ++nt)
#pragma unroll
      for (int r = 0; r < 4; ++r)
        ob[(size_t)(lhi * 4 + r) * 512 + nt * 16 + llo] = Of[nt][r] * linv[r];
  } else {
    float* op = Opart + (size_t)job * (64 * 512) + (size_t)(wave * 16) * 512;
#pragma unroll
    for (int nt = 0; nt < 32; ++nt)
#pragma unroll
      for (int r = 0; r < 4; ++r)
        op[(size_t)(lhi * 4 + r) * 512 + nt * 16 + llo] = Of[nt][r];
    if (llo == 0) {
#pragma unroll
      for (int r = 0; r < 4; ++r) {
        msum[job * 64 + wave * 16 + lhi * 4 + r] = m_i[r];
        lsum[job * 64 + wave * 16 + lhi * 4 + r] = l_i[r];
      }
    }
  }
}

// ------------------------------- merge --------------------------------------
// Combine 2-3 partials for tiles 12..31 of each batch.
__global__ __launch_bounds__(256) void merge_kernel(const float* __restrict__ Opart,
                                                    const float* __restrict__ msum,
                                                    const float* __restrict__ lsum,
                                                    float* __restrict__ out) {
  int idx = blockIdx.x * 256 + threadIdx.x;  // 8*1280*512 total
  int d = idx & 511;
  int rg = idx >> 9;        // 0..10239
  int b = rg / 1280;
  int rr = rg - b * 1280;
  int t = 12 + (rr >> 6), row = rr & 63;
  int jjb, n;
  if (t < 24) { jjb = 12 + (t - 12) * 2; n = 2; }
  else        { jjb = 36 + (t - 24) * 3; n = 3; }
  int j0 = b * 60 + jjb;
  float M = -INFINITY;
  for (int c = 0; c < n; ++c) M = fmaxf(M, msum[(j0 + c) * 64 + row]);
  float denom = 0.f, acc = 0.f;
  for (int c = 0; c < n; ++c) {
    float a = __expf(msum[(j0 + c) * 64 + row] - M);
    denom += a * lsum[(j0 + c) * 64 + row];
    acc += a * Opart[(size_t)(j0 + c) * (64 * 512) + row * 512 + d];
  }
  out[(size_t)((b << 11) + (t << 6) + row) * 512 + d] = acc / denom;
}

// ------------------------------- launcher -----------------------------------
extern "C" void kernel_launch(void* const* d_in, const int* in_sizes, int n_in,
                              void* d_out, int out_size, void* d_ws, size_t ws_size,
                              hipStream_t stream) {
  (void)in_sizes; (void)n_in; (void)out_size; (void)ws_size;
  const float* x0 = (const float*)d_in[0];
  const float* x1 = (const float*)d_in[1];
  const float* x2 = (const float*)d_in[2];
  const float* Wq = (const float*)d_in[3];
  const float* bq = (const float*)d_in[4];
  const float* Wk = (const float*)d_in[5];
  const float* bk = (const float*)d_in[6];
  float* out = (float*)d_out;
  char* ws = (char*)d_ws;
  const size_t MB = 1ull << 20;
  bf16_t* Wtq = (bf16_t*)(ws + 0 * MB);             // 1 MB
  bf16_t* Wtk = (bf16_t*)(ws + 1 * MB);             // 1 MB
  bf16_t* qw  = (bf16_t*)(ws + 2 * MB);             // 16 MB
  bf16_t* kw  = (bf16_t*)(ws + 18 * MB);            // 16 MB
  bf16_t* vT  = (bf16_t*)(ws + 34 * MB);            // 16 MB
  float* msum = (float*)(ws + 50 * MB);             // 120 KB (480*64*4)
  float* lsum = (float*)(ws + 50 * MB + (256 << 10));
  float* Opart = (float*)(ws + 51 * MB);            // 60 MB (480*64*512*4)

  hipLaunchKernelGGL(wt_kernel, dim3(1024), dim3(256), 0, stream, Wq, Wk, Wtq, Wtk);
  hipLaunchKernelGGL(proj_kernel, dim3(3072), dim3(256), 0, stream,
                     x0, x1, x2, Wtq, Wtk, bq, bk, qw, kw, vT);
  hipLaunchKernelGGL(attn_kernel, dim3(480), dim3(256), 0, stream,
                     qw, kw, vT, out, Opart, msum, lsum);
  hipLaunchKernelGGL(merge_kernel, dim3(20480), dim3(256), 0, stream,
                     Opart, msum, lsum, out);
}

// Round 3
// 622.081 us; speedup vs baseline: 1.7424x; 1.1091x over previous
//
#include <hip/hip_runtime.h>
#include <hip/hip_bf16.h>
#include <math.h>

// ---------------------------------------------------------------------------
// DotScaledAttention: q=(x0@Wq+bq)/sqrt(512); k=x1@Wk+bk; v=x2@Wk+bk;
// out = causal_softmax(q k^T) v.   B=8 N=2048 d_emb=1024 d_red=512, fp32 io.
// R3: attn = XCD-pinned batches (blockIdx&7), triple-buffered 16KB chunk
// pipeline with raw s_barrier + manual vmcnt(4) (prefetch stays in flight),
// 816 fine-grained jobs heavy-first, bf16 partials + merge.
// ---------------------------------------------------------------------------

typedef __bf16 bf16_t;
typedef __attribute__((ext_vector_type(8))) __bf16 bf16x8;
typedef __attribute__((ext_vector_type(4))) __bf16 bf16x4;
typedef __attribute__((ext_vector_type(4))) float f32x4;

#define MFMA16(a, b, c) __builtin_amdgcn_mfma_f32_16x16x32_bf16((a), (b), (c), 0, 0, 0)

#define XSTR 72  // P-buffer row stride (bf16 elems)

__device__ __forceinline__ void stage16(const void* g, void* l) {
  // async global->LDS DMA, 16B per lane; LDS dest = wave-uniform base + lane*16
  __builtin_amdgcn_global_load_lds(
      (__attribute__((address_space(1))) void*)(uintptr_t)g,
      (__attribute__((address_space(3))) void*)l, 16, 0, 0);
}

// pipeline sync: issue already done; wait newest-4-in-flight (0x0F74 =
// vmcnt(4), lgkmcnt/expcnt no-wait), raw barrier (NO vmcnt(0) drain).
#define PIPE_WAIT_MORE                          \
  {                                             \
    asm volatile("" ::: "memory");              \
    __builtin_amdgcn_s_waitcnt(0x0F74);         \
    __builtin_amdgcn_s_barrier();               \
    asm volatile("" ::: "memory");              \
  }
#define PIPE_WAIT_LAST                          \
  {                                             \
    asm volatile("" ::: "memory");              \
    __builtin_amdgcn_s_waitcnt(0x0F70);         \
    __builtin_amdgcn_s_barrier();               \
    asm volatile("" ::: "memory");              \
  }

// --------------------------- W transpose + convert --------------------------
__global__ __launch_bounds__(256) void wt_kernel(const float* __restrict__ Wq,
                                                 const float* __restrict__ Wk,
                                                 bf16_t* __restrict__ Wtq,
                                                 bf16_t* __restrict__ Wtk) {
  __shared__ float tile[32][33];
  int bid = blockIdx.x;
  int mat = bid >> 9;
  int rem = bid & 511;
  int kt = rem >> 4, nt = rem & 15;
  int k0 = kt * 32, n0 = nt * 32;
  const float* src = mat ? Wk : Wq;
  bf16_t* dst = mat ? Wtk : Wtq;
  int t = threadIdx.x;
  int r = t >> 3, c4 = (t & 7) * 4;
  float4 v = *(const float4*)(src + (k0 + r) * 512 + n0 + c4);
  tile[r][c4 + 0] = v.x; tile[r][c4 + 1] = v.y;
  tile[r][c4 + 2] = v.z; tile[r][c4 + 3] = v.w;
  __syncthreads();
  bf16x4 o;
  o[0] = (bf16_t)tile[c4 + 0][r];
  o[1] = (bf16_t)tile[c4 + 1][r];
  o[2] = (bf16_t)tile[c4 + 2][r];
  o[3] = (bf16_t)tile[c4 + 3][r];
  *(bf16x4*)(dst + (n0 + r) * 1024 + k0 + c4) = o;
}

// ------------------------------- projections --------------------------------
__global__ __launch_bounds__(256) void proj_kernel(
    const float* __restrict__ x0, const float* __restrict__ x1, const float* __restrict__ x2,
    const bf16_t* __restrict__ Wtq, const bf16_t* __restrict__ Wtk,
    const float* __restrict__ bq, const float* __restrict__ bk,
    bf16_t* __restrict__ qo, bf16_t* __restrict__ ko, bf16_t* __restrict__ vT) {
  __shared__ __align__(16) bf16_t Xs[128 * XSTR];
  __shared__ __align__(16) bf16_t Ws[64 * XSTR];
  int bid = blockIdx.x;
  int mat = bid >> 10;
  int rem = bid & 1023;
  int mblk = rem >> 3, nblk = rem & 7;
  const float* xsrc = (mat == 0) ? x0 : ((mat == 1) ? x1 : x2);
  const bf16_t* wsrc = (mat == 0) ? Wtq : Wtk;
  int tid = threadIdx.x;
  int wave = tid >> 6, lane = tid & 63, lhi = lane >> 4, llo = lane & 15;

  f32x4 acc[2][4];
#pragma unroll
  for (int i = 0; i < 2; ++i)
#pragma unroll
    for (int j = 0; j < 4; ++j) acc[i][j] = (f32x4){0.f, 0.f, 0.f, 0.f};

  int xrow = tid >> 1, xseg = tid & 1;
  int wrow = tid >> 2, wseg = tid & 3;
  const float* xbase = xsrc + (size_t)(mblk * 128 + xrow) * 1024 + xseg * 32;
  const bf16_t* wbase = wsrc + (size_t)(nblk * 64 + wrow) * 1024 + wseg * 16;

  for (int kt = 0; kt < 16; ++kt) {
    int k0 = kt * 64;
    bf16_t tmp[32];
#pragma unroll
    for (int i = 0; i < 8; ++i) {
      float4 v = *(const float4*)(xbase + k0 + i * 4);
      tmp[i * 4 + 0] = (bf16_t)v.x; tmp[i * 4 + 1] = (bf16_t)v.y;
      tmp[i * 4 + 2] = (bf16_t)v.z; tmp[i * 4 + 3] = (bf16_t)v.w;
    }
#pragma unroll
    for (int i = 0; i < 4; ++i)
      *(bf16x8*)(&Xs[xrow * XSTR + xseg * 32 + i * 8]) = *(bf16x8*)(&tmp[i * 8]);
#pragma unroll
    for (int i = 0; i < 2; ++i)
      *(bf16x8*)(&Ws[wrow * XSTR + wseg * 16 + i * 8]) = *(const bf16x8*)(wbase + k0 + i * 8);
    __syncthreads();
#pragma unroll
    for (int ks = 0; ks < 2; ++ks) {
      bf16x8 af[2], bfr[4];
#pragma unroll
      for (int mt = 0; mt < 2; ++mt)
        af[mt] = *(const bf16x8*)(&Xs[(wave * 32 + mt * 16 + llo) * XSTR + ks * 32 + lhi * 8]);
#pragma unroll
      for (int nt = 0; nt < 4; ++nt)
        bfr[nt] = *(const bf16x8*)(&Ws[(nt * 16 + llo) * XSTR + ks * 32 + lhi * 8]);
#pragma unroll
      for (int mt = 0; mt < 2; ++mt)
#pragma unroll
        for (int nt = 0; nt < 4; ++nt)
          acc[mt][nt] = MFMA16(af[mt], bfr[nt], acc[mt][nt]);
    }
    __syncthreads();
  }

  const float* bias = (mat == 0) ? bq : bk;
  float scale = (mat == 0) ? 0.044194173824159216f : 1.0f;  // 1/sqrt(512)
#pragma unroll
  for (int mt = 0; mt < 2; ++mt) {
#pragma unroll
    for (int nt = 0; nt < 4; ++nt) {
      int n = nblk * 64 + nt * 16 + llo;
      float bv = bias[n];
      int rowb = mblk * 128 + wave * 32 + mt * 16 + lhi * 4;
      float vals[4];
#pragma unroll
      for (int r = 0; r < 4; ++r) vals[r] = (acc[mt][nt][r] + bv) * scale;
      if (mat == 0) {
#pragma unroll
        for (int r = 0; r < 4; ++r) qo[(size_t)(rowb + r) * 512 + n] = (bf16_t)vals[r];
      } else if (mat == 1) {
#pragma unroll
        for (int r = 0; r < 4; ++r) ko[(size_t)(rowb + r) * 512 + n] = (bf16_t)vals[r];
      } else {
        int batch = rowb >> 11, tok = rowb & 2047;
        bf16x4 o;
        o[0] = (bf16_t)vals[0]; o[1] = (bf16_t)vals[1];
        o[2] = (bf16_t)vals[2]; o[3] = (bf16_t)vals[3];
        *(bf16x4*)(vT + (size_t)(batch * 512 + n) * 2048 + tok) = o;
      }
    }
  }
}

// ------------------------- attention: staging helpers ------------------------
// K chunk: 64 keys x 128 d (d-range cd*128..) -> 16KB buf.
// granule idx: key = idx>>4, physical seg p = idx&15, logical seg s = p^(key&7)
__device__ __forceinline__ void issueK(const bf16_t* kbase, int key0, int cd,
                                       bf16_t* buf, int wave, int lane) {
#pragma unroll
  for (int i = 0; i < 4; ++i) {
    int idx = wave * 256 + i * 64 + lane;
    int key = idx >> 4, p = idx & 15;
    int s = p ^ (key & 7);
    stage16(kbase + (size_t)(key0 + key) * 512 + cd * 128 + s * 8,
            buf + (size_t)(wave * 256 + i * 64) * 8);
  }
}
// V chunk: 128 d (cv*128..) x 64 keys -> 16KB buf.
// granule idx: dl = idx>>3, p = idx&7, s = p^(dl&7)
__device__ __forceinline__ void issueV(const bf16_t* vbase, int key0, int cv,
                                       bf16_t* buf, int wave, int lane) {
#pragma unroll
  for (int i = 0; i < 4; ++i) {
    int idx = wave * 256 + i * 64 + lane;
    int dl = idx >> 3, p = idx & 7;
    int s = p ^ (dl & 7);
    stage16(vbase + (size_t)(cv * 128 + dl) * 2048 + key0 + s * 8,
            buf + (size_t)(wave * 256 + i * 64) * 8);
  }
}

// ------------------------------- attention ----------------------------------
// 816 jobs: batch = blockIdx&7 (XCD pin), jj = blockIdx>>3 in 0..101 decodes
// (t desc from 31, n_t = ceil((t+1)/6) chunks). Block = 64 q-rows, 4 waves.
__global__ __launch_bounds__(256, 2) void attn_kernel(
    const bf16_t* __restrict__ qg, const bf16_t* __restrict__ kg,
    const bf16_t* __restrict__ vTg, float* __restrict__ out,
    bf16_t* __restrict__ Opart, float* __restrict__ msum, float* __restrict__ lsum) {
  __shared__ __align__(16) bf16_t Pipe[3][8192];       // 48KB triple buffer
  __shared__ __align__(16) bf16_t Plds[4][16 * XSTR];  // 9.2KB per-wave P

  int bid = blockIdx.x;
  int b = bid & 7, jj = bid >> 3;
  int t = 31, base = 0, n = 6;
  for (;;) {
    int nt_ = (t + 6) / 6;
    if (jj < base + nt_) { n = nt_; break; }
    base += nt_; --t;
  }
  int c = jj - base;
  int kbs = t + 1;
  int csz = (kbs + n - 1) / n;
  int kb_lo = c * csz;
  int kb_hi = min(kbs, kb_lo + csz);
  int q0 = t * 64;

  int tid = threadIdx.x;
  int wave = tid >> 6, lane = tid & 63, lhi = lane >> 4, llo = lane & 15;
  bf16_t* Pb = &Plds[wave][0];

  const bf16_t* kbase = kg + ((size_t)b << 11) * 512;
  const bf16_t* vbase = vTg + ((size_t)b << 9) * 2048;

  int bc = 0;
  issueK(kbase, kb_lo * 64, 0, &Pipe[0][0], wave, lane);

  // Q fragments (A-layout m=llo, k=lhi*8+j), rows q0+wave*16+llo, all 512 d
  const bf16_t* qrowp = qg + (size_t)((b << 11) + q0 + wave * 16 + llo) * 512;
  bf16x8 qf[16];
#pragma unroll
  for (int kk = 0; kk < 16; ++kk)
    qf[kk] = *(const bf16x8*)(qrowp + kk * 32 + lhi * 8);

  f32x4 Of[32];
#pragma unroll
  for (int i = 0; i < 32; ++i) Of[i] = (f32x4){0.f, 0.f, 0.f, 0.f};
  float m_i[4] = {-INFINITY, -INFINITY, -INFINITY, -INFINITY};
  float l_i[4] = {0.f, 0.f, 0.f, 0.f};

  for (int kb = kb_lo; kb < kb_hi; ++kb) {
    int key0 = kb * 64;
    f32x4 sf[4];
#pragma unroll
    for (int nt = 0; nt < 4; ++nt) sf[nt] = (f32x4){0.f, 0.f, 0.f, 0.f};

    // ---- QK: 4 K-chunks of 128 d ----
#pragma unroll
    for (int cd = 0; cd < 4; ++cd) {
      int nb = (bc + 1 == 3) ? 0 : bc + 1;
      if (cd < 3) issueK(kbase, key0, cd + 1, &Pipe[nb][0], wave, lane);
      else        issueV(vbase, key0, 0, &Pipe[nb][0], wave, lane);
      PIPE_WAIT_MORE;
      const bf16_t* bufc = &Pipe[bc][0];
#pragma unroll
      for (int kkl = 0; kkl < 4; ++kkl) {
#pragma unroll
        for (int nt = 0; nt < 4; ++nt) {
          bf16x8 kf = *(const bf16x8*)(bufc + (nt * 16 + llo) * 128 +
                                       (((kkl * 4 + lhi) ^ (llo & 7)) * 8));
          sf[nt] = MFMA16(qf[cd * 4 + kkl], kf, sf[nt]);
        }
      }
      bc = nb;
    }

    // ---- softmax (V0 DMA in flight underneath) ----
    if (kb == t) {  // diagonal block: causal mask
#pragma unroll
      for (int nt = 0; nt < 4; ++nt) {
        int kloc = nt * 16 + llo;
#pragma unroll
        for (int r = 0; r < 4; ++r)
          if (kloc > wave * 16 + lhi * 4 + r) sf[nt][r] = -INFINITY;
      }
    }
    float vm[4];
#pragma unroll
    for (int r = 0; r < 4; ++r) {
      vm[r] = fmaxf(fmaxf(sf[0][r], sf[1][r]), fmaxf(sf[2][r], sf[3][r]));
      vm[r] = fmaxf(vm[r], __shfl_xor(vm[r], 1, 64));
      vm[r] = fmaxf(vm[r], __shfl_xor(vm[r], 2, 64));
      vm[r] = fmaxf(vm[r], __shfl_xor(vm[r], 4, 64));
      vm[r] = fmaxf(vm[r], __shfl_xor(vm[r], 8, 64));
    }
    float alpha[4];
    int resc = 0;
#pragma unroll
    for (int r = 0; r < 4; ++r) {
      float mn = fmaxf(m_i[r], vm[r]);
      alpha[r] = __expf(m_i[r] - mn);
      m_i[r] = mn;
      resc |= (alpha[r] < 1.0f) ? 1 : 0;
    }
#pragma unroll
    for (int r = 0; r < 4; ++r) {
      float ps = 0.f;
#pragma unroll
      for (int nt = 0; nt < 4; ++nt) {
        float p = __expf(sf[nt][r] - m_i[r]);
        ps += p;
        Pb[(lhi * 4 + r) * XSTR + nt * 16 + llo] = (bf16_t)p;
      }
      l_i[r] = alpha[r] * l_i[r] + ps;
    }
    if (__any(resc)) {
#pragma unroll
      for (int i = 0; i < 32; ++i)
#pragma unroll
        for (int r = 0; r < 4; ++r) Of[i][r] *= alpha[r];
    }

    // ---- PV: 4 V-chunks of 128 d ----
#pragma unroll
    for (int cv = 0; cv < 4; ++cv) {
      int nb = (bc + 1 == 3) ? 0 : bc + 1;
      bool last = (cv == 3) && (kb + 1 >= kb_hi);
      if (cv < 3) issueV(vbase, key0, cv + 1, &Pipe[nb][0], wave, lane);
      else if (!last) issueK(kbase, key0 + 64, 0, &Pipe[nb][0], wave, lane);
      if (last) PIPE_WAIT_LAST else PIPE_WAIT_MORE;
      const bf16_t* bufc = &Pipe[bc][0];
#pragma unroll
      for (int ks = 0; ks < 2; ++ks) {
        bf16x8 pa = *(const bf16x8*)(&Pb[llo * XSTR + ks * 32 + lhi * 8]);
#pragma unroll
        for (int ntl = 0; ntl < 8; ++ntl) {
          bf16x8 bv = *(const bf16x8*)(bufc + (ntl * 16 + llo) * 64 +
                                       (((ks * 4 + lhi) ^ (llo & 7)) * 8));
          Of[cv * 8 + ntl] = MFMA16(pa, bv, Of[cv * 8 + ntl]);
        }
      }
      bc = nb;
    }
  }  // kb loop

  // l reduction across the 16 col-lanes
#pragma unroll
  for (int r = 0; r < 4; ++r) {
    l_i[r] += __shfl_xor(l_i[r], 1, 64);
    l_i[r] += __shfl_xor(l_i[r], 2, 64);
    l_i[r] += __shfl_xor(l_i[r], 4, 64);
    l_i[r] += __shfl_xor(l_i[r], 8, 64);
  }

  // Of[i] holds d-col = (i>>3)*128 + (i&7)*16 + llo
  if (n == 1) {
    float linv[4];
#pragma unroll
    for (int r = 0; r < 4; ++r) linv[r] = 1.0f / l_i[r];
    float* ob = out + (size_t)((b << 11) + q0 + wave * 16) * 512;
#pragma unroll
    for (int i = 0; i < 32; ++i) {
      int dcol = ((i >> 3) << 7) + ((i & 7) << 4) + llo;
#pragma unroll
      for (int r = 0; r < 4; ++r)
        ob[(size_t)(lhi * 4 + r) * 512 + dcol] = Of[i][r] * linv[r];
    }
  } else {
    bf16_t* op = Opart + (size_t)bid * (64 * 512) + (size_t)(wave * 16) * 512;
#pragma unroll
    for (int i = 0; i < 32; ++i) {
      int dcol = ((i >> 3) << 7) + ((i & 7) << 4) + llo;
#pragma unroll
      for (int r = 0; r < 4; ++r)
        op[(size_t)(lhi * 4 + r) * 512 + dcol] = (bf16_t)Of[i][r];
    }
    if (llo == 0) {
#pragma unroll
      for (int r = 0; r < 4; ++r) {
        msum[bid * 64 + wave * 16 + lhi * 4 + r] = m_i[r];
        lsum[bid * 64 + wave * 16 + lhi * 4 + r] = l_i[r];
      }
    }
  }
}

// ------------------------------- merge --------------------------------------
// Combine 2-6 partials for tiles 6..31 of each batch.
__global__ __launch_bounds__(256) void merge_kernel(const bf16_t* __restrict__ Opart,
                                                    const float* __restrict__ msum,
                                                    const float* __restrict__ lsum,
                                                    float* __restrict__ out) {
  int idx = blockIdx.x * 256 + threadIdx.x;  // 8*26*64*512 = 6,815,744
  int d = idx & 511;
  int rg = idx >> 9;          // 0..13311 = b(8) x t(26) x row(64)
  int b = rg / 1664;
  int rr = rg - b * 1664;
  int t = 6 + (rr >> 6), row = rr & 63;
  int base = 0;
  for (int s = 31; s > t; --s) base += (s + 6) / 6;
  int n = (t + 6) / 6;
  float M = -INFINITY;
  for (int c2 = 0; c2 < n; ++c2)
    M = fmaxf(M, msum[((base + c2) * 8 + b) * 64 + row]);
  float denom = 0.f, acc = 0.f;
  for (int c2 = 0; c2 < n; ++c2) {
    int j = (base + c2) * 8 + b;
    float a = __expf(msum[j * 64 + row] - M);
    denom += a * lsum[j * 64 + row];
    acc += a * (float)Opart[(size_t)j * (64 * 512) + row * 512 + d];
  }
  out[(size_t)((b << 11) + (t << 6) + row) * 512 + d] = acc / denom;
}

// ------------------------------- launcher -----------------------------------
extern "C" void kernel_launch(void* const* d_in, const int* in_sizes, int n_in,
                              void* d_out, int out_size, void* d_ws, size_t ws_size,
                              hipStream_t stream) {
  (void)in_sizes; (void)n_in; (void)out_size; (void)ws_size;
  const float* x0 = (const float*)d_in[0];
  const float* x1 = (const float*)d_in[1];
  const float* x2 = (const float*)d_in[2];
  const float* Wq = (const float*)d_in[3];
  const float* bq = (const float*)d_in[4];
  const float* Wk = (const float*)d_in[5];
  const float* bk = (const float*)d_in[6];
  float* out = (float*)d_out;
  char* ws = (char*)d_ws;
  const size_t MB = 1ull << 20;
  bf16_t* Wtq = (bf16_t*)(ws + 0 * MB);             // 1 MB
  bf16_t* Wtk = (bf16_t*)(ws + 1 * MB);             // 1 MB
  bf16_t* qw  = (bf16_t*)(ws + 2 * MB);             // 16 MB
  bf16_t* kw  = (bf16_t*)(ws + 18 * MB);            // 16 MB
  bf16_t* vT  = (bf16_t*)(ws + 34 * MB);            // 16 MB
  float* msum = (float*)(ws + 50 * MB);             // 209 KB (816*64*4)
  float* lsum = (float*)(ws + 50 * MB + (512 << 10));
  bf16_t* Opart = (bf16_t*)(ws + 51 * MB);          // 53.5 MB (816*64*512*2)

  hipLaunchKernelGGL(wt_kernel, dim3(1024), dim3(256), 0, stream, Wq, Wk, Wtq, Wtk);
  hipLaunchKernelGGL(proj_kernel, dim3(3072), dim3(256), 0, stream,
                     x0, x1, x2, Wtq, Wtk, bq, bk, qw, kw, vT);
  hipLaunchKernelGGL(attn_kernel, dim3(816), dim3(256), 0, stream,
                     qw, kw, vT, out, Opart, msum, lsum);
  hipLaunchKernelGGL(merge_kernel, dim3(26624), dim3(256), 0, stream,
                     Opart, msum, lsum, out);
}